// Round 1
// baseline (273.145 us; speedup 1.0000x reference)
//
#include <hip/hip_runtime.h>
#include <hip/hip_bf16.h>
#include <cstdint>
#include <cstddef>

typedef unsigned short u16;
typedef __bf16 bf16x8 __attribute__((ext_vector_type(8)));
typedef float  f32x4  __attribute__((ext_vector_type(4)));
typedef u16    u16x8  __attribute__((ext_vector_type(8)));
typedef u16    u16x4  __attribute__((ext_vector_type(4)));

#define MFMA16(A_, B_, C_) __builtin_amdgcn_mfma_f32_16x16x32_bf16((A_), (B_), (C_), 0, 0, 0)

__device__ __forceinline__ u16 f2bf(float f) {
  return __builtin_bit_cast(u16, (__bf16)f);
}

// ---------------- prep kernels ----------------

__global__ void cvt_f32_bf16(const float* __restrict__ src, u16* __restrict__ dst, int n4) {
  int i = blockIdx.x * 256 + threadIdx.x;
  if (i < n4) {
    const float4 v = ((const float4*)src)[i];
    u16x4 o;
    o[0] = f2bf(v.x); o[1] = f2bf(v.y); o[2] = f2bf(v.z); o[3] = f2bf(v.w);
    ((u16x4*)dst)[i] = o;
  }
}

__global__ void bn_prep(const float* __restrict__ g, const float* __restrict__ b,
                        const float* __restrict__ rm, const float* __restrict__ rv,
                        float* __restrict__ alpha, float* __restrict__ beta,
                        int n, float scale) {
  int i = blockIdx.x * 256 + threadIdx.x;
  if (i < n) {
    float a0 = g[i] * rsqrtf(rv[i] + 1e-5f);
    alpha[i] = a0 * scale;
    beta[i]  = (b[i] - rm[i] * a0) * scale;
  }
}

__global__ void bias_expand(const float* __restrict__ attn_bias, const int* __restrict__ idxs,
                            float* __restrict__ bias_full, int n_off) {
  int i = blockIdx.x * 256 + threadIdx.x;
  if (i < 8 * 320 * 1280) {
    int h = i / (320 * 1280);
    int r = i - h * (320 * 1280);
    bias_full[i] = attn_bias[h * n_off + idxs[r]];
  }
}

// ---------------- GEMM 1: kv = x @ W_kv^T, BN, scatter to K / V^T ----------------
// A: x_bf16 [40960][256], Wt: [1536][256] (N x K, row-major = B^T input)
// 128x128 tile, BK=64, 4 waves (2x2), each wave 64x64 via 4x4 16x16x32 MFMA frags.

__global__ __launch_bounds__(256) void gemm_kv(
    const u16* __restrict__ A, const u16* __restrict__ Wt,
    const float* __restrict__ alpha, const float* __restrict__ beta,
    u16* __restrict__ k_buf, u16* __restrict__ vt_buf) {
  __shared__ __align__(16) u16 As[128 * 72];
  __shared__ __align__(16) u16 Bs[128 * 72];
  const int tid  = threadIdx.x;
  const int lane = tid & 63;
  const int w    = tid >> 6;
  const int wr   = (w >> 1) * 64, wc = (w & 1) * 64;
  const int lr   = lane >> 4, lc = lane & 15;
  const int m0   = blockIdx.x * 128;
  const int n0   = blockIdx.y * 128;
  const int sr   = tid >> 3, sc = (tid & 7) * 8;
  f32x4 acc[4][4] = {};

  for (int kt = 0; kt < 256; kt += 64) {
    if (kt) __syncthreads();
#pragma unroll
    for (int i = 0; i < 4; ++i) {
      const int row = sr + i * 32;
      *(u16x8*)(&As[row * 72 + sc]) = *(const u16x8*)(A  + (size_t)(m0 + row) * 256 + kt + sc);
      *(u16x8*)(&Bs[row * 72 + sc]) = *(const u16x8*)(Wt + (size_t)(n0 + row) * 256 + kt + sc);
    }
    __syncthreads();
#pragma unroll
    for (int kk = 0; kk < 2; ++kk) {
      bf16x8 af[4], bff[4];
#pragma unroll
      for (int m = 0; m < 4; ++m)
        af[m] = *(const bf16x8*)(&As[(wr + m * 16 + lc) * 72 + kk * 32 + lr * 8]);
#pragma unroll
      for (int n = 0; n < 4; ++n)
        bff[n] = *(const bf16x8*)(&Bs[(wc + n * 16 + lc) * 72 + kk * 32 + lr * 8]);
#pragma unroll
      for (int m = 0; m < 4; ++m)
#pragma unroll
        for (int n = 0; n < 4; ++n)
          acc[m][n] = MFMA16(af[m], bff[n], acc[m][n]);
    }
  }

  const int jr = lr * 4;
#pragma unroll
  for (int m = 0; m < 4; ++m) {
    const int r0  = m0 + wr + m * 16 + jr;
    const int b   = r0 / 1280;
    const int np0 = r0 - b * 1280;
#pragma unroll
    for (int n = 0; n < 4; ++n) {
      const int c    = n0 + wc + n * 16 + lc;
      const float al = alpha[c], be = beta[c];
      const int head = c / 192;
      const int off  = c - head * 192;
      const size_t bh = (size_t)(b * 8 + head);
      if (off < 64) {
#pragma unroll
        for (int j = 0; j < 4; ++j)
          k_buf[(bh * 1280 + np0 + j) * 64 + off] = f2bf(acc[m][n][j] * al + be);
      } else {
        u16x4 pk;
#pragma unroll
        for (int j = 0; j < 4; ++j) pk[j] = f2bf(acc[m][n][j] * al + be);
        *(u16x4*)(&vt_buf[(bh * 128 + (off - 64)) * 1280 + np0]) = pk;
      }
    }
  }
}

// ---------------- GEMM 2: q = subsample(x) @ W_q^T, BN, *0.125 (folded) ----------------

__device__ __forceinline__ int sub_src_row(int qr) {
  if (qr < 256) return ((qr >> 4) * 64) + ((qr & 15) * 2);
  int rr = qr - 256;
  return 1024 + ((rr >> 3) * 32) + ((rr & 7) * 2);
}

__global__ __launch_bounds__(256) void gemm_q(
    const u16* __restrict__ X, const u16* __restrict__ Wt,
    const float* __restrict__ alpha, const float* __restrict__ beta,
    u16* __restrict__ q_buf) {
  __shared__ __align__(16) u16 As[128 * 72];
  __shared__ __align__(16) u16 Bs[128 * 72];
  const int tid  = threadIdx.x;
  const int lane = tid & 63;
  const int w    = tid >> 6;
  const int wr   = (w >> 1) * 64, wc = (w & 1) * 64;
  const int lr   = lane >> 4, lc = lane & 15;
  const int m0   = blockIdx.x * 128;
  const int n0   = blockIdx.y * 128;
  const int sr   = tid >> 3, sc = (tid & 7) * 8;
  f32x4 acc[4][4] = {};

  for (int kt = 0; kt < 256; kt += 64) {
    if (kt) __syncthreads();
#pragma unroll
    for (int i = 0; i < 4; ++i) {
      const int row = sr + i * 32;
      const int gr  = m0 + row;
      const int b   = gr / 320;
      const int qr  = gr - b * 320;
      const int srow = b * 1280 + sub_src_row(qr);
      *(u16x8*)(&As[row * 72 + sc]) = *(const u16x8*)(X  + (size_t)srow * 256 + kt + sc);
      *(u16x8*)(&Bs[row * 72 + sc]) = *(const u16x8*)(Wt + (size_t)(n0 + row) * 256 + kt + sc);
    }
    __syncthreads();
#pragma unroll
    for (int kk = 0; kk < 2; ++kk) {
      bf16x8 af[4], bff[4];
#pragma unroll
      for (int m = 0; m < 4; ++m)
        af[m] = *(const bf16x8*)(&As[(wr + m * 16 + lc) * 72 + kk * 32 + lr * 8]);
#pragma unroll
      for (int n = 0; n < 4; ++n)
        bff[n] = *(const bf16x8*)(&Bs[(wc + n * 16 + lc) * 72 + kk * 32 + lr * 8]);
#pragma unroll
      for (int m = 0; m < 4; ++m)
#pragma unroll
        for (int n = 0; n < 4; ++n)
          acc[m][n] = MFMA16(af[m], bff[n], acc[m][n]);
    }
  }

  const int jr = lr * 4;
#pragma unroll
  for (int m = 0; m < 4; ++m) {
#pragma unroll
    for (int n = 0; n < 4; ++n) {
      const int c    = n0 + wc + n * 16 + lc;   // < 512
      const float al = alpha[c], be = beta[c];
      const int head = c >> 6, kd = c & 63;
#pragma unroll
      for (int j = 0; j < 4; ++j) {
        const int r  = m0 + wr + m * 16 + jr + j;
        const int b  = r / 320;
        const int qr = r - b * 320;
        q_buf[((size_t)(b * 8 + head) * 320 + qr) * 64 + kd] = f2bf(acc[m][n][j] * al + be);
      }
    }
  }
}

// ---------------- attention: per (b,h,qtile of 64 rows), online softmax ----------------

__global__ __launch_bounds__(256) void attn_kernel(
    const u16* __restrict__ q_buf, const u16* __restrict__ k_buf,
    const u16* __restrict__ vt_buf, const float* __restrict__ bias_full,
    u16* __restrict__ o_buf) {
  __shared__ __align__(16) u16 Ks[64 * 72];
  __shared__ __align__(16) u16 Vs[128 * 72];
  __shared__ __align__(16) u16 Ps[4 * 16 * 72];
  const int tid  = threadIdx.x;
  const int lane = tid & 63;
  const int w    = tid >> 6;
  const int lr   = lane >> 4, lc = lane & 15;
  const int jr   = lr * 4;
  const int qt = blockIdx.x, h = blockIdx.y, b = blockIdx.z;
  const size_t bh = (size_t)(b * 8 + h);
  const int q0w   = qt * 64 + w * 16;

  bf16x8 aq0, aq1;
  {
    const u16* qp = q_buf + (bh * 320 + q0w + lc) * 64 + lr * 8;
    aq0 = *(const bf16x8*)(qp);
    aq1 = *(const bf16x8*)(qp + 32);
  }
  f32x4 oacc[8] = {};
  float mrun[4] = {-3e38f, -3e38f, -3e38f, -3e38f};
  float lrun[4] = {0.f, 0.f, 0.f, 0.f};
  const int sr = tid >> 3, sc = (tid & 7) * 8;
  u16* Pw = &Ps[w * 16 * 72];
  const float* bias_base = bias_full + ((size_t)h * 320 + q0w + jr) * 1280;

  for (int kt = 0; kt < 20; ++kt) {
    const int k0 = kt * 64;
    if (kt) __syncthreads();
#pragma unroll
    for (int i = 0; i < 2; ++i) {
      const int row = sr + i * 32;
      *(u16x8*)(&Ks[row * 72 + sc]) = *(const u16x8*)(k_buf + (bh * 1280 + k0 + row) * 64 + sc);
    }
#pragma unroll
    for (int i = 0; i < 4; ++i) {
      const int row = sr + i * 32;
      *(u16x8*)(&Vs[row * 72 + sc]) = *(const u16x8*)(vt_buf + (bh * 128 + row) * 1280 + k0 + sc);
    }
    __syncthreads();

    // S = Q K^T  (rows = q, cols = keys)
    f32x4 s[4];
#pragma unroll
    for (int n = 0; n < 4; ++n) {
      const u16* kp = &Ks[(n * 16 + lc) * 72 + lr * 8];
      f32x4 t = {};
      t = MFMA16(aq0, *(const bf16x8*)(kp), t);
      t = MFMA16(aq1, *(const bf16x8*)(kp + 32), t);
      s[n] = t;
    }

    // + bias, row max
    float p[4][4];
    float mx[4];
#pragma unroll
    for (int j = 0; j < 4; ++j) {
      const float* bp = bias_base + (size_t)j * 1280 + k0 + lc;
      float v0 = s[0][j] + bp[0];
      float v1 = s[1][j] + bp[16];
      float v2 = s[2][j] + bp[32];
      float v3 = s[3][j] + bp[48];
      p[0][j] = v0; p[1][j] = v1; p[2][j] = v2; p[3][j] = v3;
      mx[j] = fmaxf(fmaxf(v0, v1), fmaxf(v2, v3));
    }
#pragma unroll
    for (int j = 0; j < 4; ++j) {
      float m = mx[j];
      m = fmaxf(m, __shfl_xor(m, 1));
      m = fmaxf(m, __shfl_xor(m, 2));
      m = fmaxf(m, __shfl_xor(m, 4));
      m = fmaxf(m, __shfl_xor(m, 8));
      mx[j] = m;
    }
    float corr[4];
#pragma unroll
    for (int j = 0; j < 4; ++j) {
      const float mnew = fmaxf(mrun[j], mx[j]);
      corr[j] = __expf(mrun[j] - mnew);
      mrun[j] = mnew;
    }
    float ps[4];
#pragma unroll
    for (int j = 0; j < 4; ++j) {
      float acc = 0.f;
#pragma unroll
      for (int n = 0; n < 4; ++n) {
        p[n][j] = __expf(p[n][j] - mrun[j]);
        acc += p[n][j];
      }
      acc += __shfl_xor(acc, 1);
      acc += __shfl_xor(acc, 2);
      acc += __shfl_xor(acc, 4);
      acc += __shfl_xor(acc, 8);
      ps[j] = acc;
    }
#pragma unroll
    for (int j = 0; j < 4; ++j) lrun[j] = lrun[j] * corr[j] + ps[j];
#pragma unroll
    for (int nc = 0; nc < 8; ++nc)
#pragma unroll
      for (int j = 0; j < 4; ++j) oacc[nc][j] *= corr[j];

    // P -> LDS (bf16), round-trip to A-fragment layout
#pragma unroll
    for (int n = 0; n < 4; ++n)
#pragma unroll
      for (int j = 0; j < 4; ++j)
        Pw[(jr + j) * 72 + n * 16 + lc] = f2bf(p[n][j]);
    asm volatile("" ::: "memory");  // order u16 LDS stores vs bf16x8 loads (TBAA guard)
    bf16x8 pa0 = *(const bf16x8*)(&Pw[lc * 72 + lr * 8]);
    bf16x8 pa1 = *(const bf16x8*)(&Pw[lc * 72 + 32 + lr * 8]);
#pragma unroll
    for (int nc = 0; nc < 8; ++nc) {
      const u16* vp = &Vs[(nc * 16 + lc) * 72 + lr * 8];
      oacc[nc] = MFMA16(pa0, *(const bf16x8*)(vp), oacc[nc]);
      oacc[nc] = MFMA16(pa1, *(const bf16x8*)(vp + 32), oacc[nc]);
    }
  }

  float invl[4];
#pragma unroll
  for (int j = 0; j < 4; ++j) invl[j] = 1.f / lrun[j];
#pragma unroll
  for (int nc = 0; nc < 8; ++nc) {
#pragma unroll
    for (int j = 0; j < 4; ++j) {
      const float xv = oacc[nc][j] * invl[j];
      const float hs = xv * fminf(fmaxf(xv + 3.f, 0.f), 6.f) * (1.f / 6.f);
      o_buf[((size_t)b * 320 + q0w + jr + j) * 1024 + h * 128 + nc * 16 + lc] = f2bf(hs);
    }
  }
}

// ---------------- GEMM 3: out = hswish(o) @ W_p^T, BN (f32 out) ----------------

__global__ __launch_bounds__(256) void gemm_p(
    const u16* __restrict__ O, const u16* __restrict__ Wt,
    const float* __restrict__ alpha, const float* __restrict__ beta,
    float* __restrict__ out) {
  __shared__ __align__(16) u16 As[128 * 72];
  __shared__ __align__(16) u16 Bs[128 * 72];
  const int tid  = threadIdx.x;
  const int lane = tid & 63;
  const int w    = tid >> 6;
  const int wr   = (w >> 1) * 64, wc = (w & 1) * 64;
  const int lr   = lane >> 4, lc = lane & 15;
  const int m0   = blockIdx.x * 128;
  const int n0   = blockIdx.y * 128;
  const int sr   = tid >> 3, sc = (tid & 7) * 8;
  f32x4 acc[4][4] = {};

  for (int kt = 0; kt < 1024; kt += 64) {
    if (kt) __syncthreads();
#pragma unroll
    for (int i = 0; i < 4; ++i) {
      const int row = sr + i * 32;
      *(u16x8*)(&As[row * 72 + sc]) = *(const u16x8*)(O  + (size_t)(m0 + row) * 1024 + kt + sc);
      *(u16x8*)(&Bs[row * 72 + sc]) = *(const u16x8*)(Wt + (size_t)(n0 + row) * 1024 + kt + sc);
    }
    __syncthreads();
#pragma unroll
    for (int kk = 0; kk < 2; ++kk) {
      bf16x8 af[4], bff[4];
#pragma unroll
      for (int m = 0; m < 4; ++m)
        af[m] = *(const bf16x8*)(&As[(wr + m * 16 + lc) * 72 + kk * 32 + lr * 8]);
#pragma unroll
      for (int n = 0; n < 4; ++n)
        bff[n] = *(const bf16x8*)(&Bs[(wc + n * 16 + lc) * 72 + kk * 32 + lr * 8]);
#pragma unroll
      for (int m = 0; m < 4; ++m)
#pragma unroll
        for (int n = 0; n < 4; ++n)
          acc[m][n] = MFMA16(af[m], bff[n], acc[m][n]);
    }
  }

  const int jr = lr * 4;
#pragma unroll
  for (int m = 0; m < 4; ++m) {
#pragma unroll
    for (int n = 0; n < 4; ++n) {
      const int c = n0 + wc + n * 16 + lc;   // < 384
      const float al = alpha[c], be = beta[c];
#pragma unroll
      for (int j = 0; j < 4; ++j) {
        const int r = m0 + wr + m * 16 + jr + j;
        out[(size_t)r * 384 + c] = acc[m][n][j] * al + be;
      }
    }
  }
}

// ---------------- launch ----------------

extern "C" void kernel_launch(void* const* d_in, const int* in_sizes, int n_in,
                              void* d_out, int out_size, void* d_ws, size_t ws_size,
                              hipStream_t stream) {
  const float* x      = (const float*)d_in[0];
  const float* W_kv   = (const float*)d_in[1];
  const float* g_kv   = (const float*)d_in[2];
  const float* b_kv   = (const float*)d_in[3];
  const float* rm_kv  = (const float*)d_in[4];
  const float* rv_kv  = (const float*)d_in[5];
  const float* W_q    = (const float*)d_in[6];
  const float* g_q    = (const float*)d_in[7];
  const float* b_q    = (const float*)d_in[8];
  const float* rm_q   = (const float*)d_in[9];
  const float* rv_q   = (const float*)d_in[10];
  const float* W_p    = (const float*)d_in[11];
  const float* g_p    = (const float*)d_in[12];
  const float* b_p    = (const float*)d_in[13];
  const float* rm_p   = (const float*)d_in[14];
  const float* rv_p   = (const float*)d_in[15];
  const float* attn_bias = (const float*)d_in[16];
  const int*   bias_idxs = (const int*)d_in[17];
  const int n_off = in_sizes[16] / 8;

  char* ws = (char*)d_ws;
  size_t off = 0;
  auto alloc = [&](size_t bytes) -> void* {
    void* p = ws + off;
    off += (bytes + 255) & ~(size_t)255;
    return p;
  };
  u16* x_bf    = (u16*)alloc((size_t)40960 * 256 * 2);
  u16* wkv_bf  = (u16*)alloc((size_t)1536 * 256 * 2);
  u16* wq_bf   = (u16*)alloc((size_t)512 * 256 * 2);
  u16* wp_bf   = (u16*)alloc((size_t)384 * 1024 * 2);
  float* al_kv = (float*)alloc(1536 * 4);
  float* be_kv = (float*)alloc(1536 * 4);
  float* al_q  = (float*)alloc(512 * 4);
  float* be_q  = (float*)alloc(512 * 4);
  float* al_p  = (float*)alloc(384 * 4);
  float* be_p  = (float*)alloc(384 * 4);
  u16* k_buf   = (u16*)alloc((size_t)32 * 8 * 1280 * 64 * 2);
  u16* vt_buf  = (u16*)alloc((size_t)32 * 8 * 128 * 1280 * 2);
  u16* q_buf   = (u16*)alloc((size_t)32 * 8 * 320 * 64 * 2);
  float* bias_full = (float*)alloc((size_t)8 * 320 * 1280 * 4);
  u16* o_buf   = (u16*)alloc((size_t)32 * 320 * 1024 * 2);
  (void)ws_size; (void)n_in; (void)out_size;

  cvt_f32_bf16<<<(2621440 + 255) / 256, 256, 0, stream>>>(x, x_bf, 2621440);
  cvt_f32_bf16<<<(98304 + 255) / 256, 256, 0, stream>>>(W_kv, wkv_bf, 98304);
  cvt_f32_bf16<<<(32768 + 255) / 256, 256, 0, stream>>>(W_q, wq_bf, 32768);
  cvt_f32_bf16<<<(98304 + 255) / 256, 256, 0, stream>>>(W_p, wp_bf, 98304);
  bn_prep<<<6, 256, 0, stream>>>(g_kv, b_kv, rm_kv, rv_kv, al_kv, be_kv, 1536, 1.0f);
  bn_prep<<<2, 256, 0, stream>>>(g_q, b_q, rm_q, rv_q, al_q, be_q, 512, 0.125f);
  bn_prep<<<2, 256, 0, stream>>>(g_p, b_p, rm_p, rv_p, al_p, be_p, 384, 1.0f);
  bias_expand<<<(3276800 + 255) / 256, 256, 0, stream>>>(attn_bias, bias_idxs, bias_full, n_off);

  gemm_kv<<<dim3(320, 12), 256, 0, stream>>>(x_bf, wkv_bf, al_kv, be_kv, k_buf, vt_buf);
  gemm_q<<<dim3(80, 4), 256, 0, stream>>>(x_bf, wq_bf, al_q, be_q, q_buf);
  attn_kernel<<<dim3(5, 8, 32), 256, 0, stream>>>(q_buf, k_buf, vt_buf, bias_full, o_buf);
  gemm_p<<<dim3(80, 3), 256, 0, stream>>>(o_buf, wp_bf, al_p, be_p, (float*)d_out);
}